// Round 1
// 198.946 us; speedup vs baseline: 1.0363x; 1.0363x over previous
//
#include <hip/hip_runtime.h>
#include <cstddef>
#include <cstdint>

#define H 128
#define EDIM 16
#define NLAYER 3
#define NSLICE 18            // 16 edge_W slices + edge_b + root_W
#define WCOLS (NSLICE * H)   // 2304
#define PCOLS (EDIM * H)     // 2048 bf16 cols of P

typedef unsigned short ushort_t;
typedef unsigned int uint_t;
typedef __attribute__((ext_vector_type(8))) short bf16x8;
typedef __attribute__((ext_vector_type(4))) float f32x4;

__device__ __forceinline__ ushort_t f2bf(float f) {
    uint_t u = __builtin_bit_cast(uint_t, f);
    u += 0x7fffu + ((u >> 16) & 1u);   // RNE
    return (ushort_t)(u >> 16);
}
__device__ __forceinline__ float bf_lo(uint_t u) {
    return __builtin_bit_cast(float, u << 16);
}
__device__ __forceinline__ float bf_hi(uint_t u) {
    return __builtin_bit_cast(float, u & 0xffff0000u);
}

// ---- setup: blocks 0..31 histograms, 32..85 weight prep, 86..149 embed GEMM
__global__ __launch_bounds__(256) void setup_kernel(
    const int* __restrict__ dst, const int* __restrict__ batch,
    int* __restrict__ histD, float* __restrict__ cntG, int E, int N,
    const float* __restrict__ eW, const float* __restrict__ eb,
    const float* __restrict__ rW, ushort_t* __restrict__ Wt,
    const float* __restrict__ x, const float* __restrict__ nW,
    const float* __restrict__ nbias, float* __restrict__ h,
    ushort_t* __restrict__ hbf)
{
    __shared__ alignas(16) ushort_t tile[128][136];
    const int t = threadIdx.x;

    if (blockIdx.x < 32) {
        const int g = blockIdx.x * 256 + t;
        if (g < E) atomicAdd(&histD[dst[g]], 1);
        if (g < N) atomicAdd(&cntG[batch[g]], 1.f);
        return;
    }

    if (blockIdx.x < 86) {
        // weight prep: fp32 [k][o] slice -> bf16 Wt[l][n][k]
        const int b = blockIdx.x - 32;       // 0..53
        const int l = b / NSLICE, s = b % NSLICE;
        const float* S = (s < 16) ? (eW + ((size_t)l * 16 + s) * (H * H))
                       : (s == 16 ? (eb + (size_t)l * H * H)
                                  : (rW + (size_t)l * H * H));
        const int k = t >> 1, o0 = (t & 1) * 64;
#pragma unroll
        for (int j = 0; j < 64; j += 4) {
            float4 v = *(const float4*)&S[(size_t)k * H + o0 + j];
            tile[k][o0 + j + 0] = f2bf(v.x);
            tile[k][o0 + j + 1] = f2bf(v.y);
            tile[k][o0 + j + 2] = f2bf(v.z);
            tile[k][o0 + j + 3] = f2bf(v.w);
        }
        __syncthreads();
        const int n = t >> 1, k0 = (t & 1) * 64;
        ushort_t* outp = Wt + ((size_t)l * WCOLS + s * H + n) * H + k0;
#pragma unroll 8
        for (int j = 0; j < 64; ++j) outp[j] = tile[k0 + j][n];
        return;
    }

    // ---- node-embed GEMM: h = x @ node_W + node_b  (M=2048,K=32,N=128) ----
    const int b2 = blockIdx.x - 86;          // 0..63
    const int bm = (b2 >> 1) * 64;
    const int bn = (b2 & 1) * 64;
    float (*As)[68] = (float (*)[68])(void*)tile;        // 16x68 f32
    float (*Bs)[68] = ((float (*)[68])(void*)tile) + 16; // next 16x68 f32

    const int tx = t & 15, ty = t >> 4;
    float acc[4][4];
#pragma unroll
    for (int i = 0; i < 4; ++i)
#pragma unroll
        for (int j = 0; j < 4; ++j) acc[i][j] = 0.f;

    const int ka = t & 15, ma = t >> 4;
    const int nb2 = t & 63, kb = t >> 6;

    for (int k0 = 0; k0 < 32; k0 += 16) {
#pragma unroll
        for (int r = 0; r < 4; ++r)
            As[ka][ma + 16 * r] = x[(size_t)(bm + ma + 16 * r) * 32 + k0 + ka];
#pragma unroll
        for (int r = 0; r < 4; ++r)
            Bs[kb + 4 * r][nb2] = nW[(size_t)(k0 + kb + 4 * r) * H + bn + nb2];
        __syncthreads();
#pragma unroll
        for (int kk = 0; kk < 16; ++kk) {
            const float4 a4 = *(const float4*)&As[kk][ty * 4];
            const float4 b4 = *(const float4*)&Bs[kk][tx * 4];
            const float a[4] = {a4.x, a4.y, a4.z, a4.w};
            const float b[4] = {b4.x, b4.y, b4.z, b4.w};
#pragma unroll
            for (int i = 0; i < 4; ++i)
#pragma unroll
                for (int j = 0; j < 4; ++j)
                    acc[i][j] = fmaf(a[i], b[j], acc[i][j]);
        }
        __syncthreads();
    }

#pragma unroll
    for (int i = 0; i < 4; ++i) {
        const int row = bm + ty * 4 + i;
        float4 v;
        v.x = acc[i][0] + nbias[bn + tx * 4 + 0];
        v.y = acc[i][1] + nbias[bn + tx * 4 + 1];
        v.z = acc[i][2] + nbias[bn + tx * 4 + 2];
        v.w = acc[i][3] + nbias[bn + tx * 4 + 3];
        *(float4*)&h[(size_t)row * H + bn + tx * 4] = v;
        ushort_t* o = &hbf[(size_t)row * H + bn + tx * 4];
        o[0] = f2bf(v.x); o[1] = f2bf(v.y); o[2] = f2bf(v.z); o[3] = f2bf(v.w);
    }
}

// ---- bf16 MFMA GEMM: [2048,128]@Wt^T -> Pb (bf16, slices 0..15) + QR fp32 -
__global__ __launch_bounds__(256) void mfma_gemm(
    const ushort_t* __restrict__ hbf, const ushort_t* __restrict__ Wt,
    ushort_t* __restrict__ Pb, float* __restrict__ QR)
{
    __shared__ ushort_t As[64][136];
    __shared__ ushort_t Bs[64][136];
    const int tid = threadIdx.x;
    const int v0 = blockIdx.y * 64;
    const int n0 = blockIdx.x * 64;

    {
        const int row = tid >> 2, col0 = (tid & 3) * 32;
        const ushort_t* ga = hbf + (size_t)(v0 + row) * H + col0;
        const ushort_t* gb = Wt + (size_t)(n0 + row) * H + col0;
#pragma unroll
        for (int j = 0; j < 32; j += 8) {
            *(uint4*)&As[row][col0 + j] = *(const uint4*)(ga + j);
            *(uint4*)&Bs[row][col0 + j] = *(const uint4*)(gb + j);
        }
    }
    __syncthreads();

    const int wave = tid >> 6, lane = tid & 63;
    const int l15 = lane & 15, kg = lane >> 4;
    const int mrow = wave * 16 + l15;

    f32x4 acc0 = {0.f, 0.f, 0.f, 0.f};
    f32x4 acc1 = {0.f, 0.f, 0.f, 0.f};
    f32x4 acc2 = {0.f, 0.f, 0.f, 0.f};
    f32x4 acc3 = {0.f, 0.f, 0.f, 0.f};

#pragma unroll
    for (int s = 0; s < 4; ++s) {
        const int k = s * 32 + kg * 8;
        bf16x8 a = *(const bf16x8*)&As[mrow][k];
        bf16x8 b0 = *(const bf16x8*)&Bs[0 * 16 + l15][k];
        bf16x8 b1 = *(const bf16x8*)&Bs[1 * 16 + l15][k];
        bf16x8 b2 = *(const bf16x8*)&Bs[2 * 16 + l15][k];
        bf16x8 b3 = *(const bf16x8*)&Bs[3 * 16 + l15][k];
        acc0 = __builtin_amdgcn_mfma_f32_16x16x32_bf16(a, b0, acc0, 0, 0, 0);
        acc1 = __builtin_amdgcn_mfma_f32_16x16x32_bf16(a, b1, acc1, 0, 0, 0);
        acc2 = __builtin_amdgcn_mfma_f32_16x16x32_bf16(a, b2, acc2, 0, 0, 0);
        acc3 = __builtin_amdgcn_mfma_f32_16x16x32_bf16(a, b3, acc3, 0, 0, 0);
    }

    // D: col = lane&15, row = (lane>>4)*4 + reg
    const int slice = n0 >> 7;
    const int lo = n0 & 127;
    const int row0 = v0 + wave * 16 + kg * 4;
    if (slice < 16) {
        ushort_t* op = Pb + (size_t)row0 * PCOLS + slice * H + lo + l15;
#pragma unroll
        for (int r = 0; r < 4; ++r) {
            op[(size_t)r * PCOLS + 0]  = f2bf(acc0[r]);
            op[(size_t)r * PCOLS + 16] = f2bf(acc1[r]);
            op[(size_t)r * PCOLS + 32] = f2bf(acc2[r]);
            op[(size_t)r * PCOLS + 48] = f2bf(acc3[r]);
        }
    } else {
        float* op = QR + (size_t)row0 * 256 + (slice - 16) * H + lo + l15;
#pragma unroll
        for (int r = 0; r < 4; ++r) {
            op[(size_t)r * 256 + 0]  = acc0[r];
            op[(size_t)r * 256 + 16] = acc1[r];
            op[(size_t)r * 256 + 32] = acc2[r];
            op[(size_t)r * 256 + 48] = acc3[r];
        }
    }
}

// ---- edge-parallel message + atomic scatter-add into agg -------------------
// one wave per edge; lane owns channel pair (2*lane, 2*lane+1).
// msg[e,:] = sum_d ea[e,d] * P_d[src,:] + Q[src,:];  agg[dst,:] += msg
__global__ __launch_bounds__(256) void edge_msg(
    const ushort_t* __restrict__ Pb, const float* __restrict__ QR,
    const float* __restrict__ ea, const int* __restrict__ srcArr,
    const int* __restrict__ dstArr, float* __restrict__ agg, int E)
{
    const int wave = threadIdx.x >> 6, lane = threadIdx.x & 63;
    const int e = blockIdx.x * 4 + wave;
    if (e >= E) return;
    const int s  = srcArr[e];
    const int dv = dstArr[e];
    const float* eap = ea + (size_t)e * EDIM;
    const float4 w0 = *(const float4*)(eap + 0);
    const float4 w1 = *(const float4*)(eap + 4);
    const float4 w2 = *(const float4*)(eap + 8);
    const float4 w3 = *(const float4*)(eap + 12);
    const float w[16] = {w0.x, w0.y, w0.z, w0.w, w1.x, w1.y, w1.z, w1.w,
                         w2.x, w2.y, w2.z, w2.w, w3.x, w3.y, w3.z, w3.w};
    const uint_t* prow = (const uint_t*)Pb + (size_t)s * (PCOLS / 2) + lane;
    const float2 q2 = *(const float2*)(QR + (size_t)s * 256 + 2 * lane);
    float m0 = q2.x, m1 = q2.y;
#pragma unroll
    for (int d = 0; d < EDIM; ++d) {
        const uint_t u = prow[(size_t)d * 64];
        m0 = fmaf(w[d], bf_lo(u), m0);
        m1 = fmaf(w[d], bf_hi(u), m1);
    }
    atomicAdd(&agg[(size_t)dv * H + 2 * lane], m0);
    atomicAdd(&agg[(size_t)dv * H + 2 * lane + 1], m1);
}

// ---- per-node finish: xnew = agg/deg + root + bias; BN stats; re-zero agg -
// block = 256 threads covering 8 nodes (2 halves x 4 nodes), thread owns chan c
__global__ __launch_bounds__(256) void node_stats(
    float* __restrict__ agg, const float* __restrict__ QR,
    const int* __restrict__ histD, const float* __restrict__ conv_b,
    float* __restrict__ xnew, float* __restrict__ bnS, float* __restrict__ bnQ)
{
    __shared__ float sS[H];
    __shared__ float sQ[H];
    const int tid = threadIdx.x;
    const int c = tid & 127, half = tid >> 7;
    const int v0 = blockIdx.x * 8 + half * 4;
    const float cb = conv_b[c];
    float s = 0.f, q = 0.f;
#pragma unroll
    for (int j = 0; j < 4; ++j) {
        const int v = v0 + j;
        const int deg = histD[v];
        const float rc = 1.0f / (float)(deg > 0 ? deg : 1);
        const size_t ix = (size_t)v * H + c;
        const float val = agg[ix] * rc + QR[(size_t)v * 256 + H + c] + cb;
        xnew[ix] = val;
        agg[ix] = 0.f;                       // ready for next layer's scatter
        s += val;
        q += val * val;
    }
    if (half == 0) { sS[c] = s; sQ[c] = q; }
    __syncthreads();
    if (half == 1) {
        atomicAdd(&bnS[c], sS[c] + s);
        atomicAdd(&bnQ[c], sQ[c] + q);
    }
}

// ---- h += relu(bn(xnew)); emit h_bf; last layer scatters into gsum --------
__global__ __launch_bounds__(256) void bn_apply(
    float* __restrict__ h, ushort_t* __restrict__ hbf,
    const float* __restrict__ xnew,
    const float* __restrict__ bnS, const float* __restrict__ bnQ,
    const float* __restrict__ gamma, const float* __restrict__ beta,
    const int* __restrict__ batch, float* __restrict__ gsum, int N, int last)
{
    const int idx = blockIdx.x * 256 + threadIdx.x;
    const int c = idx & 127;
    const int v = idx >> 7;
    const float invN = 1.0f / (float)N;
    const float mu = bnS[c] * invN;
    const float var = bnQ[c] * invN - mu * mu;
    const float val = (xnew[idx] - mu) * rsqrtf(var + 1e-5f) * gamma[c] + beta[c];
    const float hn = h[idx] + fmaxf(val, 0.f);
    h[idx] = hn;
    hbf[idx] = f2bf(hn);
    if (last) atomicAdd(&gsum[batch[v] * H + c], hn);
}

__global__ void classifier_kernel(
    const float* __restrict__ gsum, const float* __restrict__ cntG,
    const float* __restrict__ W1, const float* __restrict__ b1,
    const float* __restrict__ W2, const float* __restrict__ b2,
    float* __restrict__ out)
{
    const int g = blockIdx.x;
    const int j = threadIdx.x;  // 64
    const float rc = 1.0f / fmaxf(cntG[g], 1.0f);
    float acc = b1[j];
#pragma unroll 8
    for (int i = 0; i < H; ++i)
        acc = fmaf(gsum[g * H + i] * rc, W1[i * 64 + j], acc);
    float pv = fmaxf(acc, 0.f) * W2[j];
#pragma unroll
    for (int off = 32; off > 0; off >>= 1)
        pv += __shfl_down(pv, off);
    if (j == 0) out[g] = pv + b2[0];
}

extern "C" void kernel_launch(void* const* d_in, const int* in_sizes, int n_in,
                              void* d_out, int out_size, void* d_ws, size_t ws_size,
                              hipStream_t stream)
{
    const float* x      = (const float*)d_in[0];
    const int*   eidx   = (const int*)  d_in[1];
    const float* eattr  = (const float*)d_in[2];
    const int*   batch  = (const int*)  d_in[3];
    const float* node_W = (const float*)d_in[4];
    const float* node_b = (const float*)d_in[5];
    const float* edge_W = (const float*)d_in[6];
    const float* edge_b = (const float*)d_in[7];
    const float* root_W = (const float*)d_in[8];
    const float* conv_b = (const float*)d_in[9];
    const float* gamma  = (const float*)d_in[10];
    const float* beta   = (const float*)d_in[11];
    const float* W1     = (const float*)d_in[12];
    const float* b1     = (const float*)d_in[13];
    const float* W2     = (const float*)d_in[14];
    const float* b2     = (const float*)d_in[15];
    float* out = (float*)d_out;

    const int N = in_sizes[0] / 32;   // 2048
    const int E = in_sizes[1] / 2;    // 8192
    const int G = out_size;           // 128

    // ---- workspace layout (all 16B aligned) ----
    int* histD  = (int*)d_ws;                         // N
    float* cntG = (float*)(histD + N);                // G
    float* bnS  = cntG + G;                           // 3*H
    float* bnQ  = bnS + NLAYER * H;                   // 3*H
    float* gsum = bnQ + NLAYER * H;                   // G*H
    float* agg  = gsum + (size_t)G * H;               // N*H
    // --- end of zero region ---
    float* h    = agg + (size_t)N * H;                // N*H
    float* xnew = h + (size_t)N * H;                  // N*H
    ushort_t* hbf = (ushort_t*)(xnew + (size_t)N * H);        // N*H
    ushort_t* Wt  = hbf + (size_t)N * H;                      // 3*WCOLS*H
    ushort_t* Pb  = Wt + (size_t)NLAYER * WCOLS * H;          // N*PCOLS
    float* QR   = (float*)(Pb + (size_t)N * PCOLS);           // N*256

    const size_t zbytes = ((size_t)N + G + 2 * NLAYER * H
                         + (size_t)G * H + (size_t)N * H) * 4;
    hipMemsetAsync(d_ws, 0, zbytes, stream);

    const int* src = eidx;
    const int* dst = eidx + E;

    // 32 hist blocks + 54 weight-prep blocks + 64 embed-GEMM blocks
    setup_kernel<<<150, 256, 0, stream>>>(
        dst, batch, histD, cntG, E, N, edge_W, edge_b, root_W, Wt,
        x, node_W, node_b, h, hbf);

    for (int l = 0; l < NLAYER; ++l) {
        mfma_gemm<<<dim3(WCOLS / 64, N / 64), 256, 0, stream>>>(
            hbf, Wt + (size_t)l * WCOLS * H, Pb, QR);
        edge_msg<<<(E + 3) / 4, 256, 0, stream>>>(
            Pb, QR, eattr, src, dst, agg, E);
        node_stats<<<N / 8, 256, 0, stream>>>(
            agg, QR, histD, conv_b + (size_t)l * H,
            xnew, bnS + l * H, bnQ + l * H);
        bn_apply<<<(N * H) / 256, 256, 0, stream>>>(
            h, hbf, xnew, bnS + l * H, bnQ + l * H,
            gamma + (size_t)l * H, beta + (size_t)l * H,
            batch, gsum, N, l == NLAYER - 1);
    }

    classifier_kernel<<<G, 64, 0, stream>>>(gsum, cntG, W1, b1, W2, b2, out);
}